// Round 1
// baseline (209.088 us; speedup 1.0000x reference)
//
#include <hip/hip_runtime.h>
#include <math.h>

#define BB 8
#define SS 4096
#define HH 1024
#define KK 2048
#define TOKW 8   // tokens per wave in score kernel

// ---------------- Kernel 1: scores = sigmoid(hs @ w) ----------------
// block = 256 (4 waves); each wave computes TOKW consecutive tokens.
// Lane l reads float4 index (l + 64*j), j=0..3 -> coalesced 1KB per instr.
__global__ __launch_bounds__(256) void score_kernel(
    const float* __restrict__ hs, const float* __restrict__ w,
    float* __restrict__ scores) {
    const int lane = threadIdx.x & 63;
    const int waveInBlock = threadIdx.x >> 6;
    const long long waveId = (long long)blockIdx.x * 4 + waveInBlock;
    const long long tok0 = waveId * TOKW;

    const float4* w4 = (const float4*)w;
    float4 wf[4];
#pragma unroll
    for (int j = 0; j < 4; ++j) wf[j] = w4[lane + 64 * j];

    const float4* h4 = (const float4*)hs;
#pragma unroll
    for (int t = 0; t < TOKW; ++t) {
        const long long tok = tok0 + t;
        const float4* hrow = h4 + tok * (HH / 4);
        double acc = 0.0;
#pragma unroll
        for (int j = 0; j < 4; ++j) {
            float4 h = hrow[lane + 64 * j];
            acc += (double)h.x * (double)wf[j].x
                 + (double)h.y * (double)wf[j].y
                 + (double)h.z * (double)wf[j].z
                 + (double)h.w * (double)wf[j].w;
        }
#pragma unroll
        for (int off = 32; off >= 1; off >>= 1)
            acc += __shfl_down(acc, off);
        if (lane == 0) {
            double sc = 1.0 / (1.0 + exp(-acc));
            scores[tok] = (float)sc;
        }
    }
}

// ---------------- Kernel 2: per-row top-K selection ----------------
// One block (256 threads) per batch row. Each thread owns the contiguous
// index chunk [tid*16, tid*16+16) in registers. Binary search on IEEE bits
// (scores all positive -> bit order == value order) for the K-th largest,
// then select: all > thr, plus lowest-index ties up to exactly K.
__global__ __launch_bounds__(256) void select_kernel(
    const float* __restrict__ scores, float* __restrict__ weights,
    float* __restrict__ maskout) {
    const int b = blockIdx.x;
    const int tid = threadIdx.x;
    const float* row = scores + b * SS;

    float v[16];
    unsigned bits[16];
#pragma unroll
    for (int i = 0; i < 16; ++i) {
        v[i] = row[tid * 16 + i];
        bits[i] = __float_as_uint(v[i]);
    }

    __shared__ int red[4];
    __shared__ int scanbuf[256];

    // largest thr with count(bits >= thr) >= K; invariant holds at init:
    // count(>=0) = S >= K ; count(>= 1.0f_bits+1) = 0 < K (sigmoid <= 1).
    unsigned lo = 0u, hi = 0x3F800001u;
    while (hi - lo > 1u) {
        unsigned mid = lo + ((hi - lo) >> 1);
        int c = 0;
#pragma unroll
        for (int i = 0; i < 16; ++i) c += (bits[i] >= mid) ? 1 : 0;
#pragma unroll
        for (int off = 32; off >= 1; off >>= 1) c += __shfl_down(c, off);
        if ((tid & 63) == 0) red[tid >> 6] = c;
        __syncthreads();
        int total = red[0] + red[1] + red[2] + red[3];
        __syncthreads();
        if (total >= KK) lo = mid; else hi = mid;
    }
    const unsigned thr = lo;

    // count strictly greater
    int cg = 0;
#pragma unroll
    for (int i = 0; i < 16; ++i) cg += (bits[i] > thr) ? 1 : 0;
#pragma unroll
    for (int off = 32; off >= 1; off >>= 1) cg += __shfl_down(cg, off);
    if ((tid & 63) == 0) red[tid >> 6] = cg;
    __syncthreads();
    const int c_gt = red[0] + red[1] + red[2] + red[3];
    __syncthreads();
    const int need = KK - c_gt;  // >= 1, <= count(bits == thr)

    // index-ordered exclusive prefix of equality counts (ties -> lowest idx)
    int ceq = 0;
#pragma unroll
    for (int i = 0; i < 16; ++i) ceq += (bits[i] == thr) ? 1 : 0;
    scanbuf[tid] = ceq;
    __syncthreads();
    if (tid == 0) {
        int run = 0;
        for (int t = 0; t < 256; ++t) {
            int x = scanbuf[t];
            scanbuf[t] = run;
            run += x;
        }
    }
    __syncthreads();

    int run = scanbuf[tid];
#pragma unroll
    for (int i = 0; i < 16; ++i) {
        bool sel;
        if (bits[i] > thr) {
            sel = true;
        } else if (bits[i] == thr) {
            sel = (run < need);
            run++;
        } else {
            sel = false;
        }
        const int idx = b * SS + tid * 16 + i;
        weights[idx] = sel ? v[i] : 0.0f;
        maskout[idx] = sel ? 1.0f : 0.0f;
    }
}

extern "C" void kernel_launch(void* const* d_in, const int* in_sizes, int n_in,
                              void* d_out, int out_size, void* d_ws, size_t ws_size,
                              hipStream_t stream) {
    const float* hs = (const float*)d_in[0];   // [B,S,H] fp32
    const float* w  = (const float*)d_in[1];   // [H] fp32
    float* out = (float*)d_out;                // [B*S] weights ++ [B*S] mask
    float* scores = (float*)d_ws;              // B*S floats = 128 KB scratch

    const int tokens = BB * SS;                         // 32768
    const int blocks1 = tokens / (TOKW * 4);            // 1024 blocks, 4 waves each
    score_kernel<<<blocks1, 256, 0, stream>>>(hs, w, scores);
    select_kernel<<<BB, 256, 0, stream>>>(scores, out, out + (size_t)BB * SS);
}

// Round 2
// 207.607 us; speedup vs baseline: 1.0071x; 1.0071x over previous
//
#include <hip/hip_runtime.h>
#include <math.h>

#define BB 8
#define SS 4096
#define HH 1024
#define KK 2048

// ---------------- Kernel 1: scores = sigmoid(hs @ w) ----------------
// One wave per token (4 waves / 256-thread block). Lane l reads float4
// index (l + 64j): each instruction covers 1 KB contiguous -> coalesced.
// Low register footprint (4 hs float4 + 4 w float4 + 4 double accs) so
// all 4 loads stay in flight and occupancy stays at 8 waves/SIMD.
__global__ __launch_bounds__(256) void score_kernel(
    const float* __restrict__ hs, const float* __restrict__ w,
    float* __restrict__ scores) {
    const int lane = threadIdx.x & 63;
    const int wv = threadIdx.x >> 6;
    const int token = blockIdx.x * 4 + wv;

    const float4* w4 = (const float4*)w;                       // 4 KB, L1-resident
    const float4* h4 = (const float4*)(hs + (size_t)token * HH);

    double a0 = 0.0, a1 = 0.0, a2 = 0.0, a3 = 0.0;
#pragma unroll
    for (int j = 0; j < 4; ++j) {
        float4 h  = h4[lane + 64 * j];
        float4 wf = w4[lane + 64 * j];
        a0 += (double)h.x * (double)wf.x;
        a1 += (double)h.y * (double)wf.y;
        a2 += (double)h.z * (double)wf.z;
        a3 += (double)h.w * (double)wf.w;
    }
    double acc = (a0 + a1) + (a2 + a3);
#pragma unroll
    for (int off = 1; off < 64; off <<= 1)
        acc += __shfl_xor(acc, off);
    if (lane == 0)
        scores[token] = (float)(1.0 / (1.0 + exp(-acc)));
}

// ---------------- Kernel 2: per-row top-K selection ----------------
// One wave (64 threads) per batch row; whole row (4096 scores) held in
// registers as float4[16]. No LDS, no __syncthreads. Binary search on
// IEEE bits (scores > 0 -> bit order == value order) for largest thr
// with count(>= thr) >= K, then select all > thr plus the lowest-index
// ties. Element index of f[m] component c on lane l is m*256 + l*4 + c;
// tie prefix is computed in exactly that (m, lane, c) order.
__global__ __launch_bounds__(64) void select_kernel(
    const float* __restrict__ scores, float* __restrict__ weights,
    float* __restrict__ maskout) {
    const int b = blockIdx.x;
    const int lane = threadIdx.x;
    const float4* row4 = (const float4*)(scores + b * SS);

    float4 f[16];
#pragma unroll
    for (int m = 0; m < 16; ++m) f[m] = row4[m * 64 + lane];

    // ---- binary search for threshold (30 iterations, register-only) ----
    unsigned lo = 0u, hi = 0x3F800001u;   // (0, 1.0f + 1ulp]: count(>=0)=S>=K, count(>=hi)=0<K
    while (hi - lo > 1u) {
        const unsigned mid = lo + ((hi - lo) >> 1);
        int c = 0;
#pragma unroll
        for (int m = 0; m < 16; ++m) {
            c += (__float_as_uint(f[m].x) >= mid);
            c += (__float_as_uint(f[m].y) >= mid);
            c += (__float_as_uint(f[m].z) >= mid);
            c += (__float_as_uint(f[m].w) >= mid);
        }
#pragma unroll
        for (int off = 32; off >= 1; off >>= 1) c += __shfl_xor(c, off);
        if (c >= KK) lo = mid; else hi = mid;
    }
    const unsigned thr = lo;

    // ---- count strictly-greater ----
    int cg = 0;
#pragma unroll
    for (int m = 0; m < 16; ++m) {
        cg += (__float_as_uint(f[m].x) > thr);
        cg += (__float_as_uint(f[m].y) > thr);
        cg += (__float_as_uint(f[m].z) > thr);
        cg += (__float_as_uint(f[m].w) > thr);
    }
#pragma unroll
    for (int off = 32; off >= 1; off >>= 1) cg += __shfl_xor(cg, off);
    const int need = KK - cg;   // ties to accept, lowest index first (>= 1)

    // ---- select + write, with index-ordered tie prefix ----
    float4* w4o = (float4*)(weights + b * SS);
    float4* m4o = (float4*)(maskout + b * SS);
    int base = 0;               // eq-count in groups < m (uniform)
#pragma unroll
    for (int m = 0; m < 16; ++m) {
        const float vals[4] = { f[m].x, f[m].y, f[m].z, f[m].w };
        unsigned u[4];
        int eq[4];
        int ec = 0;
#pragma unroll
        for (int c = 0; c < 4; ++c) {
            u[c] = __float_as_uint(vals[c]);
            eq[c] = (u[c] == thr) ? 1 : 0;
            ec += eq[c];
        }
        // inclusive prefix of ec over lanes
        int inc = ec;
#pragma unroll
        for (int off = 1; off < 64; off <<= 1) {
            int t = __shfl_up(inc, off);
            if (lane >= off) inc += t;
        }
        const int tot = __shfl(inc, 63);        // wave total (uniform)
        int r = base + inc - ec;                // eqs strictly before (m, lane, 0)
        float wout[4], mout[4];
#pragma unroll
        for (int c = 0; c < 4; ++c) {
            const bool sel = (u[c] > thr) || (eq[c] && r < need);
            r += eq[c];
            wout[c] = sel ? vals[c] : 0.0f;
            mout[c] = sel ? 1.0f : 0.0f;
        }
        base += tot;
        w4o[m * 64 + lane] = make_float4(wout[0], wout[1], wout[2], wout[3]);
        m4o[m * 64 + lane] = make_float4(mout[0], mout[1], mout[2], mout[3]);
    }
}

extern "C" void kernel_launch(void* const* d_in, const int* in_sizes, int n_in,
                              void* d_out, int out_size, void* d_ws, size_t ws_size,
                              hipStream_t stream) {
    const float* hs = (const float*)d_in[0];   // [B,S,H] fp32
    const float* w  = (const float*)d_in[1];   // [H] fp32
    float* out = (float*)d_out;                // [B*S] weights ++ [B*S] mask
    float* scores = (float*)d_ws;              // B*S floats = 128 KB scratch

    const int tokens = BB * SS;                // 32768
    score_kernel<<<tokens / 4, 256, 0, stream>>>(hs, w, scores);
    select_kernel<<<BB, 64, 0, stream>>>(scores, out, out + (size_t)BB * SS);
}